// Round 1
// baseline (1383.736 us; speedup 1.0000x reference)
//
#include <hip/hip_runtime.h>
#include <cstdint>

// Problem constants
#define NB 4
#define NC 64
#define NN 4096        // H*W
#define ND 576         // C*9
#define TILE 128
#define NTILES 32      // NN / TILE
#define KB 32          // k-chunk
#define NCHUNK 18      // ND / KB
#define NSLICE 4
#define MTPS 8         // m-tiles per slice (32/4)
#define BIGI 0x7FFFFFFF

// ws layout (float units)
#define A_BATCH (NTILES*ND*TILE)        // 2359296 floats per batch
#define INVN_OFF (NB*A_BATCH)           // 9437184
#define CANDV_OFF (INVN_OFF + NB*ND)    // 9439488
#define NCANDTOT (NB*NSLICE*NN*3)       // 196608
#define CANDI_OFF (CANDV_OFF + NCANDTOT)
// total ws: ~39.3 MB

// Exact jax top_k comparator: bigger value wins; tie -> smaller index wins.
__device__ __forceinline__ void insert_cmp(float v, int m,
    float& v0, int& i0, float& v1, int& i1, float& v2, int& i2) {
    bool beat2 = (v > v2) || (v == v2 && m < i2);
    if (beat2) {
        bool beat1 = (v > v1) || (v == v1 && m < i1);
        if (beat1) {
            v2 = v1; i2 = i1;
            bool beat0 = (v > v0) || (v == v0 && m < i0);
            if (beat0) { v1 = v0; i1 = i0; v0 = v; i0 = m; }
            else       { v1 = v;  i1 = m; }
        } else { v2 = v; i2 = m; }
    }
}

// Kernel 1: per-(b,c) windowed sums of x^2 -> inv norms for the 9 kernel offsets.
__global__ __launch_bounds__(64) void norm_kernel(const float* __restrict__ x,
                                                  float* __restrict__ ws) {
    const int bc = blockIdx.x;          // b*64 + c
    const int lane = threadIdx.x;       // = column w
    const float* xp = x + ((size_t)bc << 12);
    float colsum = 0.f, v0 = 0.f, v63 = 0.f;
    for (int h = 0; h < 64; ++h) {
        const float val = xp[(h << 6) + lane];
        const float sq = val * val;
        colsum += sq;
        if (h == 0)  v0 = sq;
        if (h == 63) v63 = sq;
    }
    float total = colsum, row0 = v0, row63 = v63;
    #pragma unroll
    for (int o = 32; o > 0; o >>= 1) {
        total += __shfl_xor(total, o);
        row0  += __shfl_xor(row0, o);
        row63 += __shfl_xor(row63, o);
    }
    const float col0  = __shfl(colsum, 0);
    const float col63 = __shfl(colsum, 63);
    const float c00 = __shfl(v0, 0),  c0e = __shfl(v0, 63);
    const float ce0 = __shfl(v63, 0), cee = __shfl(v63, 63);
    if (lane < 9) {
        const int dh = lane / 3 - 1, dw = lane % 3 - 1;
        float S = total;
        if (dh == 1)  S -= row0;    // source rows exclude row 0
        if (dh == -1) S -= row63;
        if (dw == 1)  S -= col0;
        if (dw == -1) S -= col63;
        if (dh == 1  && dw == 1)  S += c00;
        if (dh == 1  && dw == -1) S += c0e;
        if (dh == -1 && dw == 1)  S += ce0;
        if (dh == -1 && dw == -1) S += cee;
        float nrm = fmaxf(sqrtf(S), 1e-12f);
        ws[INVN_OFF + bc * 9 + lane] = 1.0f / nrm;
    }
}

// Kernel 2: materialize normalized unfold A in n-tiled k-major layout:
// A[b][nt][d][nl] with d = c*9 + p, n = nt*128+nl.
__global__ __launch_bounds__(256) void mat_kernel(const float* __restrict__ x,
                                                  float* __restrict__ ws) {
    const int bi = blockIdx.x;          // 4096 blocks = B * C * 16
    const int b = bi >> 10;
    const int c = (bi >> 4) & 63;
    const int nb = bi & 15;
    const int n = nb * 256 + threadIdx.x;
    const int h = n >> 6, w = n & 63;
    const float* xp = x + ((size_t)(b * 64 + c) << 12);
    const float* invn = ws + INVN_OFF + (b * 64 + c) * 9;
    float* Ab = ws + (size_t)b * A_BATCH + (size_t)(n >> 7) * (ND * TILE) + (n & 127);
    #pragma unroll
    for (int p = 0; p < 9; ++p) {
        const int dh = p / 3 - 1, dw = p % 3 - 1;
        const int r = h + dh, s = w + dw;
        float val = 0.f;
        if ((unsigned)r < 64u && (unsigned)s < 64u) val = xp[(r << 6) + s];
        Ab[(c * 9 + p) * TILE] = val * invn[p];
    }
}

// Kernel 3: R = A^T A tile GEMM (fp32, two-level accumulation) with fused top-3.
// Grid 512: b(4) x ntile(32) x slice(4). Each block: 128 rows x its 1024-col slice.
__global__ __launch_bounds__(256, 2) void gram_kernel(const float* __restrict__ A,
                                                      float* __restrict__ ws) {
    __shared__ float smem[12288];   // 48KB: An(16KB)+Am(16KB); reused for merge
    const int bx = blockIdx.x;
    const int b = bx >> 7;
    const int nt = (bx >> 2) & 31;
    const int s = bx & 3;
    const int tid = threadIdx.x;
    const int tx = tid & 15, ty = tid >> 4;

    const float* Ab = A + (size_t)b * A_BATCH;
    const float4* AnG = (const float4*)(Ab + nt * (ND * TILE));
    float4* An4 = (float4*)smem;
    float4* Am4 = (float4*)(smem + 4096);

    float t0v[8], t1v[8], t2v[8];
    int   t0i[8], t1i[8], t2i[8];
    #pragma unroll
    for (int i = 0; i < 8; ++i) {
        t0v[i] = t1v[i] = t2v[i] = -INFINITY;
        t0i[i] = t1i[i] = t2i[i] = BIGI;
    }

    for (int mt = 0; mt < MTPS; ++mt) {
        const int mtile = s * MTPS + mt;
        const float4* AmG = (const float4*)(Ab + mtile * (ND * TILE));
        float accT[8][8];
        #pragma unroll
        for (int i = 0; i < 8; ++i)
            #pragma unroll
            for (int j = 0; j < 8; ++j) accT[i][j] = 0.f;

        for (int kc = 0; kc < NCHUNK; ++kc) {
            __syncthreads();
            const float4* gn = AnG + kc * 1024;
            const float4* gm = AmG + kc * 1024;
            #pragma unroll
            for (int i = 0; i < 4; ++i) {
                An4[i * 256 + tid] = gn[i * 256 + tid];
                Am4[i * 256 + tid] = gm[i * 256 + tid];
            }
            __syncthreads();
            float acc[8][8];
            #pragma unroll
            for (int i = 0; i < 8; ++i)
                #pragma unroll
                for (int j = 0; j < 8; ++j) acc[i][j] = 0.f;
            #pragma unroll 8
            for (int k = 0; k < KB; ++k) {
                const float4 a0 = An4[k * 32 + ty];
                const float4 a1 = An4[k * 32 + 16 + ty];
                const float4 b0 = Am4[k * 32 + tx];
                const float4 b1 = Am4[k * 32 + 16 + tx];
                const float av[8] = {a0.x, a0.y, a0.z, a0.w, a1.x, a1.y, a1.z, a1.w};
                const float bv[8] = {b0.x, b0.y, b0.z, b0.w, b1.x, b1.y, b1.z, b1.w};
                #pragma unroll
                for (int i = 0; i < 8; ++i)
                    #pragma unroll
                    for (int j = 0; j < 8; ++j)
                        acc[i][j] = fmaf(av[i], bv[j], acc[i][j]);
            }
            #pragma unroll
            for (int i = 0; i < 8; ++i)
                #pragma unroll
                for (int j = 0; j < 8; ++j) accT[i][j] += acc[i][j];
        }
        // fold this 128x128 tile into per-row running top-3 (ascending m => strict-> exact)
        const int mb = mtile * TILE;
        #pragma unroll
        for (int j = 0; j < 8; ++j) {
            const int m = mb + ((j < 4) ? (tx * 4 + j) : (64 + tx * 4 + j - 4));
            #pragma unroll
            for (int i = 0; i < 8; ++i)
                insert_cmp(accT[i][j], m, t0v[i], t0i[i], t1v[i], t1i[i], t2v[i], t2i[i]);
        }
    }

    // merge across the 16 tx-threads sharing each row
    __syncthreads();
    float* cv = smem;                 // [16][128][3] floats
    int*   ci = (int*)(smem + 6144);  // [16][128][3] ints
    #pragma unroll
    for (int i = 0; i < 8; ++i) {
        const int row = (i < 4) ? (ty * 4 + i) : (64 + ty * 4 + i - 4);
        const int base = (tx * 128 + row) * 3;
        cv[base] = t0v[i]; cv[base + 1] = t1v[i]; cv[base + 2] = t2v[i];
        ci[base] = t0i[i]; ci[base + 1] = t1i[i]; ci[base + 2] = t2i[i];
    }
    __syncthreads();
    if (tid < TILE) {
        float v0 = -INFINITY, v1 = -INFINITY, v2 = -INFINITY;
        int i0 = BIGI, i1 = BIGI, i2 = BIGI;
        for (int t = 0; t < 16; ++t) {
            const int base = (t * 128 + tid) * 3;
            #pragma unroll
            for (int j = 0; j < 3; ++j)
                insert_cmp(cv[base + j], ci[base + j], v0, i0, v1, i1, v2, i2);
        }
        const size_t o = ((size_t)(b * NSLICE + s) * NN + nt * TILE + tid) * 3;
        ws[CANDV_OFF + o] = v0; ws[CANDV_OFF + o + 1] = v1; ws[CANDV_OFF + o + 2] = v2;
        int* wi = (int*)ws;
        wi[CANDI_OFF + o] = i0; wi[CANDI_OFF + o + 1] = i1; wi[CANDI_OFF + o + 2] = i2;
    }
}

// Kernel 4: merge slice candidates -> global top-3; 27-way attention. One wave per n.
__global__ __launch_bounds__(256) void attn_kernel(const float* __restrict__ x,
                                                   const float* __restrict__ ws,
                                                   float* __restrict__ out) {
    const int wid = threadIdx.x >> 6;
    const int lane = threadIdx.x & 63;
    const int gw = blockIdx.x * 4 + wid;   // 0..16383
    const int b = gw >> 12;
    const int n = gw & 4095;

    float v0 = -INFINITY, v1 = -INFINITY, v2 = -INFINITY;
    int i0 = BIGI, i1 = BIGI, i2 = BIGI;
    const int* wi = (const int*)ws;
    #pragma unroll
    for (int s = 0; s < NSLICE; ++s) {
        const size_t o = ((size_t)(b * NSLICE + s) * NN + n) * 3;
        #pragma unroll
        for (int j = 0; j < 3; ++j)
            insert_cmp(ws[CANDV_OFF + o + j], wi[CANDI_OFF + o + j], v0, i0, v1, i1, v2, i2);
    }
    const int idx3[3] = {i0, i1, i2};

    // per-lane feature meta for d = a*64 + lane  (torch reshape: K[...,a,c'] = xu[a*64+c'])
    int cc[9], dhh[9], dww[9];
    float inr[9];
    #pragma unroll
    for (int a = 0; a < 9; ++a) {
        const int d = a * 64 + lane;
        const int c = d / 9;
        const int p = d - c * 9;
        cc[a] = c; dhh[a] = p / 3 - 1; dww[a] = p - (p / 3) * 3 - 1;
        inr[a] = ws[INVN_OFF + b * ND + d];
    }
    const float q = x[((size_t)(b * 64 + lane) << 12) + n];

    float rv[27], sc[27];
    #pragma unroll
    for (int k = 0; k < 3; ++k) {
        const int m = idx3[k];
        const int hm = m >> 6, wm = m & 63;
        #pragma unroll
        for (int a = 0; a < 9; ++a) {
            const int r = hm + dhh[a], s2 = wm + dww[a];
            float val = 0.f;
            if ((unsigned)r < 64u && (unsigned)s2 < 64u)
                val = x[((size_t)(b * 64 + cc[a]) << 12) + (r << 6) + s2];
            const float rr = val * inr[a];
            rv[k * 9 + a] = rr;
            float t = q * rr;
            #pragma unroll
            for (int o2 = 32; o2 > 0; o2 >>= 1) t += __shfl_xor(t, o2);
            sc[k * 9 + a] = t * 0.125f;   // / sqrt(64)
        }
    }
    float mx = -INFINITY;
    #pragma unroll
    for (int u = 0; u < 27; ++u) mx = fmaxf(mx, sc[u]);
    float sum = 0.f;
    #pragma unroll
    for (int u = 0; u < 27; ++u) { const float e = expf(sc[u] - mx); sc[u] = e; sum += e; }
    const float inv = 1.0f / sum;
    float o = 0.f;
    #pragma unroll
    for (int u = 0; u < 27; ++u) o += sc[u] * rv[u];
    out[((size_t)gw << 6) + lane] = o * inv;
}

extern "C" void kernel_launch(void* const* d_in, const int* in_sizes, int n_in,
                              void* d_out, int out_size, void* d_ws, size_t ws_size,
                              hipStream_t stream) {
    (void)in_sizes; (void)n_in; (void)out_size; (void)ws_size;
    const float* x = (const float*)d_in[0];
    float* ws = (float*)d_ws;
    float* out = (float*)d_out;

    hipLaunchKernelGGL(norm_kernel, dim3(NB * NC), dim3(64), 0, stream, x, ws);
    hipLaunchKernelGGL(mat_kernel, dim3(4096), dim3(256), 0, stream, x, ws);
    hipLaunchKernelGGL(gram_kernel, dim3(512), dim3(256), 0, stream, ws, ws);
    hipLaunchKernelGGL(attn_kernel, dim3(4096), dim3(256), 0, stream, x, ws, out);
}

// Round 3
// 1250.123 us; speedup vs baseline: 1.1069x; 1.1069x over previous
//
#include <hip/hip_runtime.h>
#include <cstdint>

// Problem constants
#define NB 4
#define NC 64
#define NN 4096        // H*W
#define ND 576         // C*9
#define TILE 128
#define NTILES 32      // NN / TILE
#define KB 32          // k-chunk
#define NCHUNK 18      // ND / KB
#define NSLICE 4
#define MTPS 4         // 256-wide m-tile steps per slice (1024/256)
#define BIGI 0x7FFFFFFF

// ws layout (float units)
#define A_BATCH (NTILES*ND*TILE)        // 2359296 floats per batch
#define INVN_OFF (NB*A_BATCH)           // 9437184
#define CANDV_OFF (INVN_OFF + NB*ND)    // 9439488
#define NCANDTOT (NB*NSLICE*NN*3)       // 196608
#define CANDI_OFF (CANDV_OFF + NCANDTOT)
// total ws: ~39.3 MB

// Exact jax top_k comparator: bigger value wins; tie -> smaller index wins.
__device__ __forceinline__ void insert_cmp(float v, int m,
    float& v0, int& i0, float& v1, int& i1, float& v2, int& i2) {
    bool beat2 = (v > v2) || (v == v2 && m < i2);
    if (beat2) {
        bool beat1 = (v > v1) || (v == v1 && m < i1);
        if (beat1) {
            v2 = v1; i2 = i1;
            bool beat0 = (v > v0) || (v == v0 && m < i0);
            if (beat0) { v1 = v0; i1 = i0; v0 = v; i0 = m; }
            else       { v1 = v;  i1 = m; }
        } else { v2 = v; i2 = m; }
    }
}

// Kernel 1: per-(b,c) windowed sums of x^2 -> inv norms for the 9 kernel offsets.
__global__ __launch_bounds__(64) void norm_kernel(const float* __restrict__ x,
                                                  float* __restrict__ ws) {
    const int bc = blockIdx.x;          // b*64 + c
    const int lane = threadIdx.x;       // = column w
    const float* xp = x + ((size_t)bc << 12);
    float colsum = 0.f, v0 = 0.f, v63 = 0.f;
    for (int h = 0; h < 64; ++h) {
        const float val = xp[(h << 6) + lane];
        const float sq = val * val;
        colsum += sq;
        if (h == 0)  v0 = sq;
        if (h == 63) v63 = sq;
    }
    float total = colsum, row0 = v0, row63 = v63;
    #pragma unroll
    for (int o = 32; o > 0; o >>= 1) {
        total += __shfl_xor(total, o);
        row0  += __shfl_xor(row0, o);
        row63 += __shfl_xor(row63, o);
    }
    const float col0  = __shfl(colsum, 0);
    const float col63 = __shfl(colsum, 63);
    const float c00 = __shfl(v0, 0),  c0e = __shfl(v0, 63);
    const float ce0 = __shfl(v63, 0), cee = __shfl(v63, 63);
    if (lane < 9) {
        const int dh = lane / 3 - 1, dw = lane % 3 - 1;
        float S = total;
        if (dh == 1)  S -= row0;
        if (dh == -1) S -= row63;
        if (dw == 1)  S -= col0;
        if (dw == -1) S -= col63;
        if (dh == 1  && dw == 1)  S += c00;
        if (dh == 1  && dw == -1) S += c0e;
        if (dh == -1 && dw == 1)  S += ce0;
        if (dh == -1 && dw == -1) S += cee;
        float nrm = fmaxf(sqrtf(S), 1e-12f);
        ws[INVN_OFF + bc * 9 + lane] = 1.0f / nrm;
    }
}

// Kernel 2: materialize normalized unfold A in n-tiled k-major layout:
// A[b][nt][d][nl] with d = c*9 + p, n = nt*128+nl.
__global__ __launch_bounds__(256) void mat_kernel(const float* __restrict__ x,
                                                  float* __restrict__ ws) {
    const int bi = blockIdx.x;          // 4096 blocks = B * C * 16
    const int b = bi >> 10;
    const int c = (bi >> 4) & 63;
    const int nb = bi & 15;
    const int n = nb * 256 + threadIdx.x;
    const int h = n >> 6, w = n & 63;
    const float* xp = x + ((size_t)(b * 64 + c) << 12);
    const float* invn = ws + INVN_OFF + (b * 64 + c) * 9;
    float* Ab = ws + (size_t)b * A_BATCH + (size_t)(n >> 7) * (ND * TILE) + (n & 127);
    #pragma unroll
    for (int p = 0; p < 9; ++p) {
        const int dh = p / 3 - 1, dw = p % 3 - 1;
        const int r = h + dh, s = w + dw;
        float val = 0.f;
        if ((unsigned)r < 64u && (unsigned)s < 64u) val = xp[(r << 6) + s];
        Ab[(c * 9 + p) * TILE] = val * invn[p];
    }
}

// Kernel 3: R = A^T A tile GEMM (fp32, single-level acc, 8x16 micro-tile)
// with fused top-3. Grid 512: b(4) x ntile(32) x slice(4).
// NOTE: A and ws alias (both = d_ws) -> no __restrict__ here.
// waves_per_eu(2,2): pin occupancy to 2 waves/EU so the allocator uses the
// full 256-VGPR budget instead of spilling the 128-float accumulator.
__global__ void __launch_bounds__(256)
__attribute__((amdgpu_waves_per_eu(2, 2)))
gram_kernel(const float* A, float* ws) {
    __shared__ float smem[12288];   // An 16KB + Am 32KB = 48KB
    const int bx = blockIdx.x;
    const int b = bx >> 7;
    const int nt = (bx >> 2) & 31;
    const int s = bx & 3;
    const int tid = threadIdx.x;
    const int tx = tid & 15, ty = tid >> 4;

    const float* Ab = A + (size_t)b * A_BATCH;
    const float4* AnG = (const float4*)(Ab + nt * (ND * TILE));
    float4* An4 = (float4*)smem;            // [k][32] float4
    float4* Am4 = (float4*)(smem + 4096);   // [k][64] float4

    float t0v[8], t1v[8], t2v[8];
    int   t0i[8], t1i[8], t2i[8];
    #pragma unroll
    for (int i = 0; i < 8; ++i) {
        t0v[i] = t1v[i] = t2v[i] = -INFINITY;
        t0i[i] = t1i[i] = t2i[i] = BIGI;
    }

    for (int mt = 0; mt < MTPS; ++mt) {
        const int mpair = s * MTPS + mt;          // which 256-col group
        const float4* Am0G = (const float4*)(Ab + (2 * mpair) * (ND * TILE));
        const float4* Am1G = (const float4*)(Ab + (2 * mpair + 1) * (ND * TILE));
        float acc[8][16];
        #pragma unroll
        for (int i = 0; i < 8; ++i)
            #pragma unroll
            for (int j = 0; j < 16; ++j) acc[i][j] = 0.f;

        for (int kc = 0; kc < NCHUNK; ++kc) {
            __syncthreads();
            const float4* gn = AnG + kc * 1024;
            const float4* gm0 = Am0G + kc * 1024;
            const float4* gm1 = Am1G + kc * 1024;
            #pragma unroll
            for (int i = 0; i < 4; ++i) {
                const int idx = i * 256 + tid;
                An4[idx] = gn[idx];
                Am4[(idx >> 5) * 64 + (idx & 31)] = gm0[idx];
                Am4[(idx >> 5) * 64 + 32 + (idx & 31)] = gm1[idx];
            }
            __syncthreads();
            #pragma unroll 2
            for (int k = 0; k < KB; ++k) {
                const float4 a0 = An4[k * 32 + ty];
                const float4 a1 = An4[k * 32 + 16 + ty];
                const float4 b0 = Am4[k * 64 + tx];
                const float4 b1 = Am4[k * 64 + 16 + tx];
                const float4 b2 = Am4[k * 64 + 32 + tx];
                const float4 b3 = Am4[k * 64 + 48 + tx];
                const float av[8] = {a0.x, a0.y, a0.z, a0.w, a1.x, a1.y, a1.z, a1.w};
                const float bv[16] = {b0.x, b0.y, b0.z, b0.w, b1.x, b1.y, b1.z, b1.w,
                                      b2.x, b2.y, b2.z, b2.w, b3.x, b3.y, b3.z, b3.w};
                #pragma unroll
                for (int i = 0; i < 8; ++i)
                    #pragma unroll
                    for (int j = 0; j < 16; ++j)
                        acc[i][j] = fmaf(av[i], bv[j], acc[i][j]);
            }
        }
        // fold this 128x256 tile into per-row running top-3
        const int mb = mpair * 256;
        #pragma unroll
        for (int j = 0; j < 16; ++j) {
            const int m = mb + (j >> 2) * 64 + tx * 4 + (j & 3);
            #pragma unroll
            for (int i = 0; i < 8; ++i)
                insert_cmp(acc[i][j], m, t0v[i], t0i[i], t1v[i], t1i[i], t2v[i], t2i[i]);
        }
    }

    // merge across the 16 tx-lanes sharing each row (contiguous 16-lane subgroup)
    #pragma unroll
    for (int i = 0; i < 8; ++i) {
        #pragma unroll
        for (int o = 1; o < 16; o <<= 1) {
            const float pv0 = __shfl_xor(t0v[i], o);
            const float pv1 = __shfl_xor(t1v[i], o);
            const float pv2 = __shfl_xor(t2v[i], o);
            const int pi0 = __shfl_xor(t0i[i], o);
            const int pi1 = __shfl_xor(t1i[i], o);
            const int pi2 = __shfl_xor(t2i[i], o);
            insert_cmp(pv0, pi0, t0v[i], t0i[i], t1v[i], t1i[i], t2v[i], t2i[i]);
            insert_cmp(pv1, pi1, t0v[i], t0i[i], t1v[i], t1i[i], t2v[i], t2i[i]);
            insert_cmp(pv2, pi2, t0v[i], t0i[i], t1v[i], t1i[i], t2v[i], t2i[i]);
        }
    }
    if (tx == 0) {
        int* wi = (int*)ws;
        #pragma unroll
        for (int i = 0; i < 8; ++i) {
            const int row = ty * 4 + (i & 3) + ((i < 4) ? 0 : 64);
            const size_t o = ((size_t)(b * NSLICE + s) * NN + nt * TILE + row) * 3;
            ws[CANDV_OFF + o] = t0v[i]; ws[CANDV_OFF + o + 1] = t1v[i]; ws[CANDV_OFF + o + 2] = t2v[i];
            wi[CANDI_OFF + o] = t0i[i]; wi[CANDI_OFF + o + 1] = t1i[i]; wi[CANDI_OFF + o + 2] = t2i[i];
        }
    }
}

// Kernel 4: merge slice candidates -> global top-3; 27-way attention. One wave per n.
__global__ __launch_bounds__(256) void attn_kernel(const float* __restrict__ x,
                                                   const float* __restrict__ ws,
                                                   float* __restrict__ out) {
    const int wid = threadIdx.x >> 6;
    const int lane = threadIdx.x & 63;
    const int gw = blockIdx.x * 4 + wid;   // 0..16383
    const int b = gw >> 12;
    const int n = gw & 4095;

    float v0 = -INFINITY, v1 = -INFINITY, v2 = -INFINITY;
    int i0 = BIGI, i1 = BIGI, i2 = BIGI;
    const int* wi = (const int*)ws;
    #pragma unroll
    for (int s = 0; s < NSLICE; ++s) {
        const size_t o = ((size_t)(b * NSLICE + s) * NN + n) * 3;
        #pragma unroll
        for (int j = 0; j < 3; ++j)
            insert_cmp(ws[CANDV_OFF + o + j], wi[CANDI_OFF + o + j], v0, i0, v1, i1, v2, i2);
    }
    const int idx3[3] = {i0, i1, i2};

    // per-lane feature meta for d = a*64 + lane  (torch reshape: K[...,a,c'] = xu[a*64+c'])
    int cc[9], dhh[9], dww[9];
    float inr[9];
    #pragma unroll
    for (int a = 0; a < 9; ++a) {
        const int d = a * 64 + lane;
        const int c = d / 9;
        const int p = d - c * 9;
        cc[a] = c; dhh[a] = p / 3 - 1; dww[a] = p - (p / 3) * 3 - 1;
        inr[a] = ws[INVN_OFF + b * ND + d];
    }
    const float q = x[((size_t)(b * 64 + lane) << 12) + n];

    float rv[27], sc[27];
    #pragma unroll
    for (int k = 0; k < 3; ++k) {
        const int m = idx3[k];
        const int hm = m >> 6, wm = m & 63;
        #pragma unroll
        for (int a = 0; a < 9; ++a) {
            const int r = hm + dhh[a], s2 = wm + dww[a];
            float val = 0.f;
            if ((unsigned)r < 64u && (unsigned)s2 < 64u)
                val = x[((size_t)(b * 64 + cc[a]) << 12) + (r << 6) + s2];
            const float rr = val * inr[a];
            rv[k * 9 + a] = rr;
            float t = q * rr;
            #pragma unroll
            for (int o2 = 32; o2 > 0; o2 >>= 1) t += __shfl_xor(t, o2);
            sc[k * 9 + a] = t * 0.125f;   // / sqrt(64)
        }
    }
    float mx = -INFINITY;
    #pragma unroll
    for (int u = 0; u < 27; ++u) mx = fmaxf(mx, sc[u]);
    float sum = 0.f;
    #pragma unroll
    for (int u = 0; u < 27; ++u) { const float e = expf(sc[u] - mx); sc[u] = e; sum += e; }
    const float inv = 1.0f / sum;
    float o = 0.f;
    #pragma unroll
    for (int u = 0; u < 27; ++u) o += sc[u] * rv[u];
    out[((size_t)gw << 6) + lane] = o * inv;
}

extern "C" void kernel_launch(void* const* d_in, const int* in_sizes, int n_in,
                              void* d_out, int out_size, void* d_ws, size_t ws_size,
                              hipStream_t stream) {
    (void)in_sizes; (void)n_in; (void)out_size; (void)ws_size;
    const float* x = (const float*)d_in[0];
    float* ws = (float*)d_ws;
    float* out = (float*)d_out;

    hipLaunchKernelGGL(norm_kernel, dim3(NB * NC), dim3(64), 0, stream, x, ws);
    hipLaunchKernelGGL(mat_kernel, dim3(4096), dim3(256), 0, stream, x, ws);
    hipLaunchKernelGGL(gram_kernel, dim3(512), dim3(256), 0, stream, ws, ws);
    hipLaunchKernelGGL(attn_kernel, dim3(4096), dim3(256), 0, stream, x, ws, out);
}

// Round 4
// 692.959 us; speedup vs baseline: 1.9968x; 1.8040x over previous
//
#include <hip/hip_runtime.h>
#include <cstdint>

typedef short short8 __attribute__((ext_vector_type(8)));
typedef float f32x16 __attribute__((ext_vector_type(16)));

// Problem constants
#define NB 4
#define NN 4096
#define ND 576
#define BIGI 0x7FFFFFFF
#define NSLICE 4

// ws layout: A_hi (bf16) [b][tile32][kc18][row128][k32] = 9437184 shorts,
// then A_lo same size; then (float units):
#define INVN_OFF 9437184
#define CANDV_OFF 9439488
#define CANDI_OFF 9636096
// total = 9832704 floats = 39.33 MB (identical footprint to round 1 -> fits)

#define MFMA __builtin_amdgcn_mfma_f32_32x32x16_bf16

__device__ __forceinline__ unsigned short f2bf(float f) {
    unsigned u = __float_as_uint(f);
    u += 0x7FFFu + ((u >> 16) & 1u);   // round-to-nearest-even
    return (unsigned short)(u >> 16);
}

// Exact jax top_k comparator: bigger value wins; tie -> smaller index wins.
__device__ __forceinline__ void insert_cmp(float v, int m,
    float& v0, int& i0, float& v1, int& i1, float& v2, int& i2) {
    bool beat2 = (v > v2) || (v == v2 && m < i2);
    if (beat2) {
        bool beat1 = (v > v1) || (v == v1 && m < i1);
        if (beat1) {
            v2 = v1; i2 = i1;
            bool beat0 = (v > v0) || (v == v0 && m < i0);
            if (beat0) { v1 = v0; i1 = i0; v0 = v; i0 = m; }
            else       { v1 = v;  i1 = m; }
        } else { v2 = v; i2 = m; }
    }
}

// Kernel 1: per-(b,c) windowed sums of x^2 -> inv norms for the 9 kernel offsets.
__global__ __launch_bounds__(64) void norm_kernel(const float* __restrict__ x,
                                                  float* __restrict__ ws) {
    const int bc = blockIdx.x;          // b*64 + c
    const int lane = threadIdx.x;       // = column w
    const float* xp = x + ((size_t)bc << 12);
    float colsum = 0.f, v0 = 0.f, v63 = 0.f;
    for (int h = 0; h < 64; ++h) {
        const float val = xp[(h << 6) + lane];
        const float sq = val * val;
        colsum += sq;
        if (h == 0)  v0 = sq;
        if (h == 63) v63 = sq;
    }
    float total = colsum, row0 = v0, row63 = v63;
    #pragma unroll
    for (int o = 32; o > 0; o >>= 1) {
        total += __shfl_xor(total, o);
        row0  += __shfl_xor(row0, o);
        row63 += __shfl_xor(row63, o);
    }
    const float col0  = __shfl(colsum, 0);
    const float col63 = __shfl(colsum, 63);
    const float c00 = __shfl(v0, 0),  c0e = __shfl(v0, 63);
    const float ce0 = __shfl(v63, 0), cee = __shfl(v63, 63);
    if (lane < 9) {
        const int dh = lane / 3 - 1, dw = lane % 3 - 1;
        float S = total;
        if (dh == 1)  S -= row0;
        if (dh == -1) S -= row63;
        if (dw == 1)  S -= col0;
        if (dw == -1) S -= col63;
        if (dh == 1  && dw == 1)  S += c00;
        if (dh == 1  && dw == -1) S += c0e;
        if (dh == -1 && dw == 1)  S += ce0;
        if (dh == -1 && dw == -1) S += cee;
        float nrm = fmaxf(sqrtf(S), 1e-12f);
        ws[INVN_OFF + bc * 9 + lane] = 1.0f / nrm;
    }
}

// Kernel 2: split-bf16 materialization. blockIdx = (b*32+nt)*18+kc.
// Output chunk layout: A[b][tile][kc][row128][k32] bf16, hi and lo planes.
__global__ __launch_bounds__(256) void mat_kernel(const float* __restrict__ x,
                                                  float* __restrict__ ws) {
    const int bi = blockIdx.x;             // 2304 blocks
    const int b = bi / 576;
    const int rem = bi - b * 576;
    const int nt = rem / 18;
    const int kc = rem - nt * 18;
    unsigned short* AH = (unsigned short*)ws;
    unsigned short* AL = AH + 9437184;
    const float* invn = ws + INVN_OFF + b * 576;
    const int tid = threadIdx.x;
    #pragma unroll
    for (int hf2 = 0; hf2 < 2; ++hf2) {
        const int c = tid + hf2 * 256;     // 16B chunk 0..511
        const int row = c >> 2, k0 = (c & 3) * 8;
        const int n = nt * 128 + row;
        const int h = n >> 6, wc = n & 63;
        union { unsigned short us[8]; float4 f4; } uh, ul;
        #pragma unroll
        for (int j = 0; j < 8; ++j) {
            const int d = kc * 32 + k0 + j;
            const int ch = d / 9;
            const int p = d - ch * 9;
            const int r = h + p / 3 - 1, s2 = wc + p % 3 - 1;
            float val = 0.f;
            if ((unsigned)r < 64u && (unsigned)s2 < 64u)
                val = x[((size_t)(b * 64 + ch) << 12) + (r << 6) + s2];
            val *= invn[d];
            const unsigned short hb = f2bf(val);
            const float hfv = __uint_as_float(((unsigned)hb) << 16);
            const unsigned short lb = f2bf(val - hfv);
            uh.us[j] = hb; ul.us[j] = lb;
        }
        ((float4*)AH)[(size_t)bi * 512 + c] = uh.f4;
        ((float4*)AL)[(size_t)bi * 512 + c] = ul.f4;
    }
}

// --- gram helpers ---
// Stage one contiguous 8KB (b,tile,kc) region into padded LDS rows (36 shorts/row).
__device__ __forceinline__ void stage_region(unsigned short* dst,
                                             const unsigned short* gsrc, int tid) {
    const float4* g = (const float4*)gsrc;
    #pragma unroll
    for (int i = 0; i < 2; ++i) {
        const int c = tid + i * 256;       // 16B chunk 0..511
        const float4 v = g[c];
        float2* d = (float2*)(dst + (c >> 2) * 36 + (c & 3) * 8);
        d[0] = make_float2(v.x, v.y);
        d[1] = make_float2(v.z, v.w);
    }
}

__device__ __forceinline__ short8 ldfrag(const unsigned short* p) {
    union { short8 s8; float2 f2[2]; } u;
    const float2* q = (const float2*)p;
    u.f2[0] = q[0]; u.f2[1] = q[1];
    return u.s8;
}

// Kernel 3: R = A^T A via split-bf16 MFMA (hh + hl + lh), fused top-3.
// Grid 512 = b(4) x nt(32) x slice(4). Block: 128 n-rows x 1024 m-cols
// (4 mt steps of 256). 4 waves, wave tile = 128n x 64m.
// A-operand = Am rows (m), B-operand = An rows (n):
// C/D: m_part = (reg&3)+8*(reg>>2)+4*(lane>>5), n_part = lane&31  [m74/m101]
__global__ void __launch_bounds__(256, 2) gram_kernel(float* ws) {
    __shared__ unsigned short sm[27648];   // 54KB: AnH|AnL (128r) AmH|AmL (256r), 36 sh/row
    const int bx = blockIdx.x;
    const int b = bx >> 7;
    const int nt = (bx >> 2) & 31;
    const int s = bx & 3;
    const int tid = threadIdx.x;
    const int w = tid >> 6, lane = tid & 63;
    const int l31 = lane & 31, kh2 = lane >> 5;

    const unsigned short* AH = (const unsigned short*)ws;
    const unsigned short* AL = AH + 9437184;

    // LDS region bases (shorts)
    const int AnH = 0, AnL = 4608, AmH = 9216, AmL = 18432;
    // frag address components (shorts): row*36 + kh2*8 (+ tileoff + h*16)
    const int afr = (w * 64 + l31) * 36 + kh2 * 8;   // Am side (+mi*1152)
    const int bfr = l31 * 36 + kh2 * 8;              // An side (+ni*1152)

    const int nRegBase = (b * 32 + nt) * 18;

    float t0v[4], t1v[4], t2v[4];
    int   t0i[4], t1i[4], t2i[4];
    #pragma unroll
    for (int i = 0; i < 4; ++i) {
        t0v[i] = t1v[i] = t2v[i] = -INFINITY;
        t0i[i] = t1i[i] = t2i[i] = BIGI;
    }

    for (int mt = 0; mt < 4; ++mt) {
        const int mm0 = (s * 4 + mt) * 2;            // 128-row m-tile pair
        const int mReg0 = (b * 32 + mm0) * 18;
        const int mReg1 = mReg0 + 18;

        f32x16 acc[2][4];
        #pragma unroll
        for (int mi = 0; mi < 2; ++mi)
            #pragma unroll
            for (int ni = 0; ni < 4; ++ni)
                #pragma unroll
                for (int e = 0; e < 16; ++e) acc[mi][ni][e] = 0.f;

        for (int kc = 0; kc < 18; ++kc) {
            __syncthreads();
            stage_region(sm + AnH,        AH + (size_t)(nRegBase + kc) * 4096, tid);
            stage_region(sm + AnL,        AL + (size_t)(nRegBase + kc) * 4096, tid);
            stage_region(sm + AmH,        AH + (size_t)(mReg0 + kc) * 4096, tid);
            stage_region(sm + AmH + 4608, AH + (size_t)(mReg1 + kc) * 4096, tid);
            stage_region(sm + AmL,        AL + (size_t)(mReg0 + kc) * 4096, tid);
            stage_region(sm + AmL + 4608, AL + (size_t)(mReg1 + kc) * 4096, tid);
            __syncthreads();
            #pragma unroll
            for (int h = 0; h < 2; ++h) {
                short8 amh[2], aml[2];
                #pragma unroll
                for (int mi = 0; mi < 2; ++mi) {
                    amh[mi] = ldfrag(sm + AmH + afr + mi * 1152 + h * 16);
                    aml[mi] = ldfrag(sm + AmL + afr + mi * 1152 + h * 16);
                }
                #pragma unroll
                for (int ni = 0; ni < 4; ++ni) {
                    const short8 bh = ldfrag(sm + AnH + bfr + ni * 1152 + h * 16);
                    const short8 bl = ldfrag(sm + AnL + bfr + ni * 1152 + h * 16);
                    #pragma unroll
                    for (int mi = 0; mi < 2; ++mi) {
                        acc[mi][ni] = MFMA(amh[mi], bh, acc[mi][ni], 0, 0, 0);
                        acc[mi][ni] = MFMA(amh[mi], bl, acc[mi][ni], 0, 0, 0);
                        acc[mi][ni] = MFMA(aml[mi], bh, acc[mi][ni], 0, 0, 0);
                    }
                }
            }
        }
        // fold acc into per-lane top-3 (per ni; n = ni*32 + l31)
        const int mbase = (s * 4 + mt) * 256 + w * 64 + kh2 * 4;
        #pragma unroll
        for (int ni = 0; ni < 4; ++ni)
            #pragma unroll
            for (int mi = 0; mi < 2; ++mi)
                #pragma unroll
                for (int v = 0; v < 16; ++v) {
                    const int m = mbase + mi * 32 + (v & 3) + 8 * (v >> 2);
                    insert_cmp(acc[mi][ni][v], m,
                               t0v[ni], t0i[ni], t1v[ni], t1i[ni], t2v[ni], t2i[ni]);
                }
    }

    // merge the two kh2 halves (same n, disjoint m) via shfl
    #pragma unroll
    for (int ni = 0; ni < 4; ++ni) {
        const float pv0 = __shfl_xor(t0v[ni], 32);
        const float pv1 = __shfl_xor(t1v[ni], 32);
        const float pv2 = __shfl_xor(t2v[ni], 32);
        const int pi0 = __shfl_xor(t0i[ni], 32);
        const int pi1 = __shfl_xor(t1i[ni], 32);
        const int pi2 = __shfl_xor(t2i[ni], 32);
        insert_cmp(pv0, pi0, t0v[ni], t0i[ni], t1v[ni], t1i[ni], t2v[ni], t2i[ni]);
        insert_cmp(pv1, pi1, t0v[ni], t0i[ni], t1v[ni], t1i[ni], t2v[ni], t2i[ni]);
        insert_cmp(pv2, pi2, t0v[ni], t0i[ni], t1v[ni], t1i[ni], t2v[ni], t2i[ni]);
    }
    // cross-wave merge through LDS (each wave owns a 64-wide m slice)
    __syncthreads();
    float* cv = (float*)sm;              // [w4][ni4][l32][3] floats
    int*   ci = (int*)sm + 1536;
    if (kh2 == 0) {
        #pragma unroll
        for (int ni = 0; ni < 4; ++ni) {
            const int base = ((w * 4 + ni) * 32 + l31) * 3;
            cv[base] = t0v[ni]; cv[base + 1] = t1v[ni]; cv[base + 2] = t2v[ni];
            ci[base] = t0i[ni]; ci[base + 1] = t1i[ni]; ci[base + 2] = t2i[ni];
        }
    }
    __syncthreads();
    if (tid < 128) {
        const int ni = tid >> 5, l = tid & 31;
        float v0 = -INFINITY, v1 = -INFINITY, v2 = -INFINITY;
        int i0 = BIGI, i1 = BIGI, i2 = BIGI;
        #pragma unroll
        for (int w2 = 0; w2 < 4; ++w2) {
            const int base = ((w2 * 4 + ni) * 32 + l) * 3;
            #pragma unroll
            for (int j = 0; j < 3; ++j)
                insert_cmp(cv[base + j], ci[base + j], v0, i0, v1, i1, v2, i2);
        }
        const int n_local = ni * 32 + l;
        const size_t o = ((size_t)(b * NSLICE + s) * NN + nt * 128 + n_local) * 3;
        ws[CANDV_OFF + o] = v0; ws[CANDV_OFF + o + 1] = v1; ws[CANDV_OFF + o + 2] = v2;
        int* wi = (int*)ws;
        wi[CANDI_OFF + o] = i0; wi[CANDI_OFF + o + 1] = i1; wi[CANDI_OFF + o + 2] = i2;
    }
}

// Kernel 4: merge slice candidates -> global top-3; 27-way attention. One wave per n.
__global__ __launch_bounds__(256) void attn_kernel(const float* __restrict__ x,
                                                   const float* __restrict__ ws,
                                                   float* __restrict__ out) {
    const int wid = threadIdx.x >> 6;
    const int lane = threadIdx.x & 63;
    const int gw = blockIdx.x * 4 + wid;   // 0..16383
    const int b = gw >> 12;
    const int n = gw & 4095;

    float v0 = -INFINITY, v1 = -INFINITY, v2 = -INFINITY;
    int i0 = BIGI, i1 = BIGI, i2 = BIGI;
    const int* wi = (const int*)ws;
    #pragma unroll
    for (int s = 0; s < NSLICE; ++s) {
        const size_t o = ((size_t)(b * NSLICE + s) * NN + n) * 3;
        #pragma unroll
        for (int j = 0; j < 3; ++j)
            insert_cmp(ws[CANDV_OFF + o + j], wi[CANDI_OFF + o + j], v0, i0, v1, i1, v2, i2);
    }
    const int idx3[3] = {i0, i1, i2};

    // per-lane feature meta for d = a*64 + lane  (torch reshape: K[...,a,c'] = xu[a*64+c'])
    int cc[9], dhh[9], dww[9];
    float inr[9];
    #pragma unroll
    for (int a = 0; a < 9; ++a) {
        const int d = a * 64 + lane;
        const int c = d / 9;
        const int p = d - c * 9;
        cc[a] = c; dhh[a] = p / 3 - 1; dww[a] = p - (p / 3) * 3 - 1;
        inr[a] = ws[INVN_OFF + b * ND + d];
    }
    const float q = x[((size_t)(b * 64 + lane) << 12) + n];

    float rv[27], sc[27];
    #pragma unroll
    for (int k = 0; k < 3; ++k) {
        const int m = idx3[k];
        const int hm = m >> 6, wm = m & 63;
        #pragma unroll
        for (int a = 0; a < 9; ++a) {
            const int r = hm + dhh[a], s2 = wm + dww[a];
            float val = 0.f;
            if ((unsigned)r < 64u && (unsigned)s2 < 64u)
                val = x[((size_t)(b * 64 + cc[a]) << 12) + (r << 6) + s2];
            const float rr = val * inr[a];
            rv[k * 9 + a] = rr;
            float t = q * rr;
            #pragma unroll
            for (int o2 = 32; o2 > 0; o2 >>= 1) t += __shfl_xor(t, o2);
            sc[k * 9 + a] = t * 0.125f;   // / sqrt(64)
        }
    }
    float mx = -INFINITY;
    #pragma unroll
    for (int u = 0; u < 27; ++u) mx = fmaxf(mx, sc[u]);
    float sum = 0.f;
    #pragma unroll
    for (int u = 0; u < 27; ++u) { const float e = expf(sc[u] - mx); sc[u] = e; sum += e; }
    const float inv = 1.0f / sum;
    float o = 0.f;
    #pragma unroll
    for (int u = 0; u < 27; ++u) o += sc[u] * rv[u];
    out[((size_t)gw << 6) + lane] = o * inv;
}

extern "C" void kernel_launch(void* const* d_in, const int* in_sizes, int n_in,
                              void* d_out, int out_size, void* d_ws, size_t ws_size,
                              hipStream_t stream) {
    (void)in_sizes; (void)n_in; (void)out_size; (void)ws_size;
    const float* x = (const float*)d_in[0];
    float* ws = (float*)d_ws;
    float* out = (float*)d_out;

    hipLaunchKernelGGL(norm_kernel, dim3(NB * 64), dim3(64), 0, stream, x, ws);
    hipLaunchKernelGGL(mat_kernel, dim3(2304), dim3(256), 0, stream, x, ws);
    hipLaunchKernelGGL(gram_kernel, dim3(512), dim3(256), 0, stream, ws);
    hipLaunchKernelGGL(attn_kernel, dim3(4096), dim3(256), 0, stream, x, ws, out);
}

// Round 5
// 662.565 us; speedup vs baseline: 2.0885x; 1.0459x over previous
//
#include <hip/hip_runtime.h>
#include <cstdint>

typedef short short8 __attribute__((ext_vector_type(8)));
typedef float f32x16 __attribute__((ext_vector_type(16)));

// Problem constants
#define NB 4
#define NN 4096
#define ND 576
#define BIGI 0x7FFFFFFF
#define NSLICE 4

// ws layout: A_hi (bf16) [b][tile32][kc18][512 chunks of 16B] = 9437184 shorts,
// then A_lo same size; then (float units):
#define INVN_OFF 9437184
#define CANDV_OFF 9439488
#define CANDI_OFF 9636096
// total = 9832704 floats = 39.33 MB
// Chunk swizzle (baked into layout): chunk g = r*4 + c', source chunk
// c = c' ^ ((r>>1)&3), i.e. source k-span = c*8..c*8+7 of row r.

#define MFMA __builtin_amdgcn_mfma_f32_32x32x16_bf16

__device__ __forceinline__ unsigned short f2bf(float f) {
    unsigned u = __float_as_uint(f);
    u += 0x7FFFu + ((u >> 16) & 1u);   // round-to-nearest-even
    return (unsigned short)(u >> 16);
}

__device__ __forceinline__ void gload_lds16(const void* g, void* l) {
    __builtin_amdgcn_global_load_lds(
        (const __attribute__((address_space(1))) void*)g,
        (__attribute__((address_space(3))) void*)l, 16, 0, 0);
}

// Exact jax top_k comparator: bigger value wins; tie -> smaller index wins.
__device__ __forceinline__ void insert_cmp(float v, int m,
    float& v0, int& i0, float& v1, int& i1, float& v2, int& i2) {
    bool beat2 = (v > v2) || (v == v2 && m < i2);
    if (beat2) {
        bool beat1 = (v > v1) || (v == v1 && m < i1);
        if (beat1) {
            v2 = v1; i2 = i1;
            bool beat0 = (v > v0) || (v == v0 && m < i0);
            if (beat0) { v1 = v0; i1 = i0; v0 = v; i0 = m; }
            else       { v1 = v;  i1 = m; }
        } else { v2 = v; i2 = m; }
    }
}

// Kernel 1: per-(b,c) windowed sums of x^2 -> inv norms for the 9 kernel offsets.
__global__ __launch_bounds__(64) void norm_kernel(const float* __restrict__ x,
                                                  float* __restrict__ ws) {
    const int bc = blockIdx.x;          // b*64 + c
    const int lane = threadIdx.x;       // = column w
    const float* xp = x + ((size_t)bc << 12);
    float colsum = 0.f, v0 = 0.f, v63 = 0.f;
    for (int h = 0; h < 64; ++h) {
        const float val = xp[(h << 6) + lane];
        const float sq = val * val;
        colsum += sq;
        if (h == 0)  v0 = sq;
        if (h == 63) v63 = sq;
    }
    float total = colsum, row0 = v0, row63 = v63;
    #pragma unroll
    for (int o = 32; o > 0; o >>= 1) {
        total += __shfl_xor(total, o);
        row0  += __shfl_xor(row0, o);
        row63 += __shfl_xor(row63, o);
    }
    const float col0  = __shfl(colsum, 0);
    const float col63 = __shfl(colsum, 63);
    const float c00 = __shfl(v0, 0),  c0e = __shfl(v0, 63);
    const float ce0 = __shfl(v63, 0), cee = __shfl(v63, 63);
    if (lane < 9) {
        const int dh = lane / 3 - 1, dw = lane % 3 - 1;
        float S = total;
        if (dh == 1)  S -= row0;
        if (dh == -1) S -= row63;
        if (dw == 1)  S -= col0;
        if (dw == -1) S -= col63;
        if (dh == 1  && dw == 1)  S += c00;
        if (dh == 1  && dw == -1) S += c0e;
        if (dh == -1 && dw == 1)  S += ce0;
        if (dh == -1 && dw == -1) S += cee;
        float nrm = fmaxf(sqrtf(S), 1e-12f);
        ws[INVN_OFF + bc * 9 + lane] = 1.0f / nrm;
    }
}

// Kernel 2: split-bf16 materialization with baked chunk swizzle.
// blockIdx = (b*32+nt)*18+kc. Region = 512 chunks of 16B (8 bf16).
__global__ __launch_bounds__(256) void mat_kernel(const float* __restrict__ x,
                                                  float* __restrict__ ws) {
    const int bi = blockIdx.x;             // 2304 blocks
    const int b = bi / 576;
    const int rem = bi - b * 576;
    const int nt = rem / 18;
    const int kc = rem - nt * 18;
    unsigned short* AH = (unsigned short*)ws;
    unsigned short* AL = AH + 9437184;
    const float* invn = ws + INVN_OFF + b * 576;
    const int tid = threadIdx.x;
    #pragma unroll
    for (int hf2 = 0; hf2 < 2; ++hf2) {
        const int g = tid + hf2 * 256;     // output chunk 0..511
        const int row = g >> 2, cp = g & 3;
        const int c = cp ^ ((row >> 1) & 3);    // source chunk (swizzle)
        const int k0 = c * 8;
        const int n = nt * 128 + row;
        const int h = n >> 6, wc = n & 63;
        union { unsigned short us[8]; float4 f4; } uh, ul;
        #pragma unroll
        for (int j = 0; j < 8; ++j) {
            const int d = kc * 32 + k0 + j;
            const int ch = d / 9;
            const int p = d - ch * 9;
            const int r = h + p / 3 - 1, s2 = wc + p % 3 - 1;
            float val = 0.f;
            if ((unsigned)r < 64u && (unsigned)s2 < 64u)
                val = x[((size_t)(b * 64 + ch) << 12) + (r << 6) + s2];
            val *= invn[d];
            const unsigned short hb = f2bf(val);
            const float hfv = __uint_as_float(((unsigned)hb) << 16);
            const unsigned short lb = f2bf(val - hfv);
            uh.us[j] = hb; ul.us[j] = lb;
        }
        ((float4*)AH)[(size_t)bi * 512 + g] = uh.f4;
        ((float4*)AL)[(size_t)bi * 512 + g] = ul.f4;
    }
}

__device__ __forceinline__ short8 ldfrag(const short* p) {
    union { short8 s8; float4 f4; } u;
    u.f4 = *(const float4*)p;
    return u.s8;
}

// Kernel 3: R = A^T A via split-bf16 MFMA (hh + hl + lh), fused top-3.
// Grid 512 = b(4) x nt(32) x slice(4). Block: 128 n-rows x 1024 m-cols
// (4 mt steps of 256). 4 waves, wave tile = 128n x 64m.
// Staging via global_load_lds (16B, identity lane-ordered copy).
// C/D: m_part = (reg&3)+8*(reg>>2)+4*(lane>>5), n_part = lane&31  [HW-verified r4]
__global__ void __launch_bounds__(256, 2) gram_kernel(float* ws) {
    __shared__ short sm[24576];   // 48KB: AnH(8K) AnL(8K) AmH(16K) AmL(16K) bytes
    const int bx = blockIdx.x;
    const int b = bx >> 7;
    const int nt = (bx >> 2) & 31;
    const int s = bx & 3;
    const int tid = threadIdx.x;
    const int w = tid >> 6, lane = tid & 63;
    const int l31 = lane & 31, kh2 = lane >> 5;

    const unsigned short* AH = (const unsigned short*)ws;
    const unsigned short* AL = AH + 9437184;

    // LDS region bases (shorts)
    const int AnH = 0, AnL = 4096, AmH = 8192, AmL = 16384;   // Am: t0 then t1 (+4096)
    const int nRegBase = (b * 32 + nt) * 18;

    float t0v[4], t1v[4], t2v[4];
    int   t0i[4], t1i[4], t2i[4];
    #pragma unroll
    for (int i = 0; i < 4; ++i) {
        t0v[i] = t1v[i] = t2v[i] = -INFINITY;
        t0i[i] = t1i[i] = t2i[i] = BIGI;
    }

    // per-lane frag LDS offsets (shorts), swizzled chunk addressing:
    // frag(row, c) at row*32 + (c ^ ((row>>1)&3))*8, c = kh2 + 2h
    int aoff[2][2][2];   // [mi][h] Am (within 8K tile region; +tile*4096 added below)
    int boff[4][2];      // [ni][h] An
    #pragma unroll
    for (int mi = 0; mi < 2; ++mi)
        #pragma unroll
        for (int h = 0; h < 2; ++h) {
            const int row = w * 64 + mi * 32 + l31;      // 0..255
            const int rl = row & 127, rt = row >> 7;
            const int c = kh2 + 2 * h;
            aoff[mi][h][0] = rt * 4096 + rl * 32 + (c ^ ((rl >> 1) & 3)) * 8;
            aoff[mi][h][1] = 0; // unused
        }
    #pragma unroll
    for (int ni = 0; ni < 4; ++ni)
        #pragma unroll
        for (int h = 0; h < 2; ++h) {
            const int row = ni * 32 + l31;               // 0..127
            const int c = kh2 + 2 * h;
            boff[ni][h] = row * 32 + (c ^ ((row >> 1) & 3)) * 8;
        }

    for (int mt = 0; mt < 4; ++mt) {
        const int mm0 = (s * 4 + mt) * 2;            // 128-row m-tile pair
        const int mReg0 = (b * 32 + mm0) * 18;
        const int mReg1 = mReg0 + 18;

        f32x16 acc[2][4];
        #pragma unroll
        for (int mi = 0; mi < 2; ++mi)
            #pragma unroll
            for (int ni = 0; ni < 4; ++ni)
                #pragma unroll
                for (int e = 0; e < 16; ++e) acc[mi][ni][e] = 0.f;

        for (int kc = 0; kc < 18; ++kc) {
            __syncthreads();
            // stage 6 x 8KB regions; per wave 2 instrs/region, 1KB each
            {
                const int i0 = w * 2, i1 = w * 2 + 1;
                const int lo0 = i0 * 512, lo1 = i1 * 512;          // LDS shorts
                const int go0 = lo0 + lane * 8, go1 = lo1 + lane * 8; // global shorts
                const unsigned short* gAnH = AH + (size_t)(nRegBase + kc) * 4096;
                const unsigned short* gAnL = AL + (size_t)(nRegBase + kc) * 4096;
                const unsigned short* gM0H = AH + (size_t)(mReg0 + kc) * 4096;
                const unsigned short* gM1H = AH + (size_t)(mReg1 + kc) * 4096;
                const unsigned short* gM0L = AL + (size_t)(mReg0 + kc) * 4096;
                const unsigned short* gM1L = AL + (size_t)(mReg1 + kc) * 4096;
                gload_lds16(gAnH + go0, sm + AnH + lo0);
                gload_lds16(gAnH + go1, sm + AnH + lo1);
                gload_lds16(gAnL + go0, sm + AnL + lo0);
                gload_lds16(gAnL + go1, sm + AnL + lo1);
                gload_lds16(gM0H + go0, sm + AmH + lo0);
                gload_lds16(gM0H + go1, sm + AmH + lo1);
                gload_lds16(gM1H + go0, sm + AmH + 4096 + lo0);
                gload_lds16(gM1H + go1, sm + AmH + 4096 + lo1);
                gload_lds16(gM0L + go0, sm + AmL + lo0);
                gload_lds16(gM0L + go1, sm + AmL + lo1);
                gload_lds16(gM1L + go0, sm + AmL + 4096 + lo0);
                gload_lds16(gM1L + go1, sm + AmL + 4096 + lo1);
            }
            __syncthreads();
            #pragma unroll
            for (int h = 0; h < 2; ++h) {
                short8 amh[2], aml[2];
                #pragma unroll
                for (int mi = 0; mi < 2; ++mi) {
                    amh[mi] = ldfrag(sm + AmH + aoff[mi][h][0]);
                    aml[mi] = ldfrag(sm + AmL + aoff[mi][h][0]);
                }
                #pragma unroll
                for (int ni = 0; ni < 4; ++ni) {
                    const short8 bh = ldfrag(sm + AnH + boff[ni][h]);
                    const short8 bl = ldfrag(sm + AnL + boff[ni][h]);
                    #pragma unroll
                    for (int mi = 0; mi < 2; ++mi) {
                        acc[mi][ni] = MFMA(amh[mi], bh, acc[mi][ni], 0, 0, 0);
                        acc[mi][ni] = MFMA(amh[mi], bl, acc[mi][ni], 0, 0, 0);
                        acc[mi][ni] = MFMA(aml[mi], bh, acc[mi][ni], 0, 0, 0);
                    }
                }
            }
        }
        // fold acc into per-lane top-3 (per ni; n = ni*32 + l31)
        const int mbase = (s * 4 + mt) * 256 + w * 64 + kh2 * 4;
        #pragma unroll
        for (int ni = 0; ni < 4; ++ni)
            #pragma unroll
            for (int mi = 0; mi < 2; ++mi)
                #pragma unroll
                for (int v = 0; v < 16; ++v) {
                    const int m = mbase + mi * 32 + (v & 3) + 8 * (v >> 2);
                    insert_cmp(acc[mi][ni][v], m,
                               t0v[ni], t0i[ni], t1v[ni], t1i[ni], t2v[ni], t2i[ni]);
                }
    }

    // merge the two kh2 halves (same n, disjoint m) via shfl
    #pragma unroll
    for (int ni = 0; ni < 4; ++ni) {
        const float pv0 = __shfl_xor(t0v[ni], 32);
        const float pv1 = __shfl_xor(t1v[ni], 32);
        const float pv2 = __shfl_xor(t2v[ni], 32);
        const int pi0 = __shfl_xor(t0i[ni], 32);
        const int pi1 = __shfl_xor(t1i[ni], 32);
        const int pi2 = __shfl_xor(t2i[ni], 32);
        insert_cmp(pv0, pi0, t0v[ni], t0i[ni], t1v[ni], t1i[ni], t2v[ni], t2i[ni]);
        insert_cmp(pv1, pi1, t0v[ni], t0i[ni], t1v[ni], t1i[ni], t2v[ni], t2i[ni]);
        insert_cmp(pv2, pi2, t0v[ni], t0i[ni], t1v[ni], t1i[ni], t2v[ni], t2i[ni]);
    }
    // cross-wave merge through LDS (each wave owns a 64-wide m slice)
    __syncthreads();
    float* cv = (float*)sm;              // [w4][ni4][l32][3] floats
    int*   ci = (int*)sm + 1536;
    if (kh2 == 0) {
        #pragma unroll
        for (int ni = 0; ni < 4; ++ni) {
            const int base = ((w * 4 + ni) * 32 + l31) * 3;
            cv[base] = t0v[ni]; cv[base + 1] = t1v[ni]; cv[base + 2] = t2v[ni];
            ci[base] = t0i[ni]; ci[base + 1] = t1i[ni]; ci[base + 2] = t2i[ni];
        }
    }
    __syncthreads();
    if (tid < 128) {
        const int ni = tid >> 5, l = tid & 31;
        float v0 = -INFINITY, v1 = -INFINITY, v2 = -INFINITY;
        int i0 = BIGI, i1 = BIGI, i2 = BIGI;
        #pragma unroll
        for (int w2 = 0; w2 < 4; ++w2) {
            const int base = ((w2 * 4 + ni) * 32 + l) * 3;
            #pragma unroll
            for (int j = 0; j < 3; ++j)
                insert_cmp(cv[base + j], ci[base + j], v0, i0, v1, i1, v2, i2);
        }
        const int n_local = ni * 32 + l;
        const size_t o = ((size_t)(b * NSLICE + s) * NN + nt * 128 + n_local) * 3;
        ws[CANDV_OFF + o] = v0; ws[CANDV_OFF + o + 1] = v1; ws[CANDV_OFF + o + 2] = v2;
        int* wi = (int*)ws;
        wi[CANDI_OFF + o] = i0; wi[CANDI_OFF + o + 1] = i1; wi[CANDI_OFF + o + 2] = i2;
    }
}

// Kernel 4: merge slice candidates -> global top-3; 27-way attention. One wave per n.
__global__ __launch_bounds__(256) void attn_kernel(const float* __restrict__ x,
                                                   const float* __restrict__ ws,
                                                   float* __restrict__ out) {
    const int wid = threadIdx.x >> 6;
    const int lane = threadIdx.x & 63;
    const int gw = blockIdx.x * 4 + wid;   // 0..16383
    const int b = gw >> 12;
    const int n = gw & 4095;

    float v0 = -INFINITY, v1 = -INFINITY, v2 = -INFINITY;
    int i0 = BIGI, i1 = BIGI, i2 = BIGI;
    const int* wi = (const int*)ws;
    #pragma unroll
    for (int s = 0; s < NSLICE; ++s) {
        const size_t o = ((size_t)(b * NSLICE + s) * NN + n) * 3;
        #pragma unroll
        for (int j = 0; j < 3; ++j)
            insert_cmp(ws[CANDV_OFF + o + j], wi[CANDI_OFF + o + j], v0, i0, v1, i1, v2, i2);
    }
    const int idx3[3] = {i0, i1, i2};

    // per-lane feature meta for d = a*64 + lane  (torch reshape: K[...,a,c'] = xu[a*64+c'])
    int cc[9], dhh[9], dww[9];
    float inr[9];
    #pragma unroll
    for (int a = 0; a < 9; ++a) {
        const int d = a * 64 + lane;
        const int c = d / 9;
        const int p = d - c * 9;
        cc[a] = c; dhh[a] = p / 3 - 1; dww[a] = p - (p / 3) * 3 - 1;
        inr[a] = ws[INVN_OFF + b * ND + d];
    }
    const float q = x[((size_t)(b * 64 + lane) << 12) + n];

    float rv[27], sc[27];
    #pragma unroll
    for (int k = 0; k < 3; ++k) {
        const int m = idx3[k];
        const int hm = m >> 6, wm = m & 63;
        #pragma unroll
        for (int a = 0; a < 9; ++a) {
            const int r = hm + dhh[a], s2 = wm + dww[a];
            float val = 0.f;
            if ((unsigned)r < 64u && (unsigned)s2 < 64u)
                val = x[((size_t)(b * 64 + cc[a]) << 12) + (r << 6) + s2];
            const float rr = val * inr[a];
            rv[k * 9 + a] = rr;
            float t = q * rr;
            #pragma unroll
            for (int o2 = 32; o2 > 0; o2 >>= 1) t += __shfl_xor(t, o2);
            sc[k * 9 + a] = t * 0.125f;   // / sqrt(64)
        }
    }
    float mx = -INFINITY;
    #pragma unroll
    for (int u = 0; u < 27; ++u) mx = fmaxf(mx, sc[u]);
    float sum = 0.f;
    #pragma unroll
    for (int u = 0; u < 27; ++u) { const float e = expf(sc[u] - mx); sc[u] = e; sum += e; }
    const float inv = 1.0f / sum;
    float o = 0.f;
    #pragma unroll
    for (int u = 0; u < 27; ++u) o += sc[u] * rv[u];
    out[((size_t)gw << 6) + lane] = o * inv;
}

extern "C" void kernel_launch(void* const* d_in, const int* in_sizes, int n_in,
                              void* d_out, int out_size, void* d_ws, size_t ws_size,
                              hipStream_t stream) {
    (void)in_sizes; (void)n_in; (void)out_size; (void)ws_size;
    const float* x = (const float*)d_in[0];
    float* ws = (float*)d_ws;
    float* out = (float*)d_out;

    hipLaunchKernelGGL(norm_kernel, dim3(NB * 64), dim3(64), 0, stream, x, ws);
    hipLaunchKernelGGL(mat_kernel, dim3(2304), dim3(256), 0, stream, x, ws);
    hipLaunchKernelGGL(gram_kernel, dim3(512), dim3(256), 0, stream, ws);
    hipLaunchKernelGGL(attn_kernel, dim3(4096), dim3(256), 0, stream, x, ws, out);
}